// Round 6
// baseline (60.596 us; speedup 1.0000x reference)
//
#include <hip/hip_runtime.h>

// u_mul_v: out[e, :] = h[src[e], :] * h[dst[e], :]
// h: [10000, 128] f32, src/dst: [640000] int32, out: [640000, 128] f32.
//
// Structure (round 4/5 wins, 59.0 us): 2-way feature-column split across
// XCD groups (blockIdx%8 ~ XCD; XCDs 0-3 -> f4-cols [0,16), 4-7 ->
// [16,32)) so each XCD's L2 holds a 2.56 MB half of h (fixes the 126 MB
// h-thrash seen in round 3). Each thread owns 8 consecutive edges;
// indices load as 4x int4; nontemporal stores; exact-division grid.
//
// Round-6 delta: software-pipeline gathers/stores at depth 2 instead of
// the full-drain sched_barrier. Stores start after 2 gather round-trips
// (was 8), live f32x4 pairs 8 -> 3 (VGPR ~90 -> ~50, occupancy up), and
// in-order vmcnt drains stores progressively. If this is neutral, the
// kernel is HBM-write-bound at ~5.8-6.0 TB/s => roofline.

using f32x4 = __attribute__((ext_vector_type(4))) float;
using i32x4 = __attribute__((ext_vector_type(4))) int;

constexpr int U = 8;
constexpr int BLOCK = 256;
constexpr int EDGES_PER_BLOCK = BLOCK * U / 16;   // 128

__global__ __launch_bounds__(BLOCK) void u_mul_v_split(
    const f32x4* __restrict__ h4,
    const int* __restrict__ src,
    const int* __restrict__ dst,
    f32x4* __restrict__ out4)
{
    const int b = blockIdx.x;
    const int r = b & 7;                      // ~ XCD id
    const int half = r >> 2;                  // 0: f4-cols [0,16), 1: [16,32)
    const int bh = ((b >> 3) << 2) + (r & 3); // within-half block index
    const int t = threadIdx.x;

    const int e0 = bh * EDGES_PER_BLOCK + (t >> 4) * U;  // first of 8 edges
    const int c  = (t & 15) + (half << 4);               // f4 column

    // Index loads: 4x int4 (16 lanes broadcast each line)
    i32x4 s_lo = *(const i32x4*)&src[e0];
    i32x4 s_hi = *(const i32x4*)&src[e0 + 4];
    i32x4 d_lo = *(const i32x4*)&dst[e0];
    i32x4 d_hi = *(const i32x4*)&dst[e0 + 4];
    __builtin_amdgcn_sched_barrier(0);

    f32x4 a[U], bb[U];

    // Prologue: gathers for u=0,1
#pragma unroll
    for (int u = 0; u < 2; u++) {
        int es = s_lo[u], ed = d_lo[u];
        a[u]  = h4[es * 32 + c];
        bb[u] = h4[ed * 32 + c];
    }

    // Steady state: gather u+2, store u  (depth-2 pipeline, static indices)
#pragma unroll
    for (int u = 0; u < U - 2; u++) {
        int v = u + 2;
        int es = (v < 4) ? s_lo[v & 3] : s_hi[v & 3];
        int ed = (v < 4) ? d_lo[v & 3] : d_hi[v & 3];
        a[v]  = h4[es * 32 + c];
        bb[v] = h4[ed * 32 + c];
        __builtin_nontemporal_store(a[u] * bb[u], &out4[(e0 + u) * 32 + c]);
    }

    // Epilogue: store u=6,7
#pragma unroll
    for (int u = U - 2; u < U; u++) {
        __builtin_nontemporal_store(a[u] * bb[u], &out4[(e0 + u) * 32 + c]);
    }
}

// Generic fallback (any shape).
__global__ __launch_bounds__(BLOCK) void u_mul_v_generic(
    const f32x4* __restrict__ h4,
    const int* __restrict__ src,
    const int* __restrict__ dst,
    f32x4* __restrict__ out4,
    int n_f4)
{
    int stride = gridDim.x * BLOCK;
    for (int i = blockIdx.x * BLOCK + threadIdx.x; i < n_f4; i += stride) {
        int e = i >> 5, cc = i & 31;
        f32x4 a = h4[src[e] * 32 + cc];
        f32x4 bv = h4[dst[e] * 32 + cc];
        out4[i] = a * bv;
    }
}

extern "C" void kernel_launch(void* const* d_in, const int* in_sizes, int n_in,
                              void* d_out, int out_size, void* d_ws, size_t ws_size,
                              hipStream_t stream) {
    const f32x4* h4 = (const f32x4*)d_in[0];
    const int* src  = (const int*)d_in[1];
    const int* dst  = (const int*)d_in[2];
    f32x4* out4     = (f32x4*)d_out;

    int n_edges = in_sizes[1];            // 640000
    int n_f4 = n_edges * 32;

    if (n_edges % EDGES_PER_BLOCK == 0) {
        int g_half = n_edges / EDGES_PER_BLOCK;   // 5000
        int grid = 2 * g_half;                    // 10000 blocks
        u_mul_v_split<<<grid, BLOCK, 0, stream>>>(h4, src, dst, out4);
    } else {
        u_mul_v_generic<<<2048, BLOCK, 0, stream>>>(h4, src, dst, out4, n_f4);
    }
}

// Round 7
// 57.497 us; speedup vs baseline: 1.0539x; 1.0539x over previous
//
#include <hip/hip_runtime.h>

// u_mul_v: out[e, :] = h[src[e], :] * h[dst[e], :]
// h: [10000, 128] f32, src/dst: [640000] int32, out: [640000, 128] f32.
//
// FINAL (round-5 structure, 59.0 us = best; round-6 depth-2 pipeline
// regressed to 60.6 -> reverted).
//
// Why this is the roofline: compulsory write = 327.7 MB; measured ceilings
// on this chip: fill 7.0 TB/s, copy 6.3 TB/s -> ~52-55 us achievable for
// our 16:1 write:read mix. 59 us = 5.8 TB/s effective, ~8% over.
// Levers tested: h L2-residency (the big one: FETCH 126 MB -> ~15 MB via
// 2-way XCD column split), MLP depth U=4/8, phase clustering, idx
// vectorization (int4), nt-store vs cached, nt-idx (regressed), depth-2
// sw pipeline (regressed), bounds-check elimination.
//
// Structure:
//  - blockIdx%8 ~ XCD (CDNA4 round-robin): XCDs 0-3 own f4-cols [0,16),
//    XCDs 4-7 own [16,32). Per-XCD h working set 2.56 MB < 4 MiB L2.
//  - 16 lanes per edge-group; each thread owns 8 consecutive edges.
//  - Index loads as 4x int4; all 16 gathers clustered; nt stores.
//  - Exact-division grid (640000 % 128 == 0); generic fallback otherwise.

using f32x4 = __attribute__((ext_vector_type(4))) float;
using i32x4 = __attribute__((ext_vector_type(4))) int;

constexpr int U = 8;
constexpr int BLOCK = 256;
constexpr int EDGES_PER_BLOCK = BLOCK * U / 16;   // 128

__global__ __launch_bounds__(BLOCK) void u_mul_v_split(
    const f32x4* __restrict__ h4,
    const int* __restrict__ src,
    const int* __restrict__ dst,
    f32x4* __restrict__ out4)
{
    const int b = blockIdx.x;
    const int r = b & 7;                      // ~ XCD id
    const int half = r >> 2;                  // 0: f4-cols [0,16), 1: [16,32)
    const int bh = ((b >> 3) << 2) + (r & 3); // within-half block index
    const int t = threadIdx.x;

    const int e0 = bh * EDGES_PER_BLOCK + (t >> 4) * U;  // first of 8 edges
    const int c  = (t & 15) + (half << 4);               // f4 column

    // Phase 1: vectorized index loads (16 lanes broadcast each line)
    i32x4 s_lo = *(const i32x4*)&src[e0];
    i32x4 s_hi = *(const i32x4*)&src[e0 + 4];
    i32x4 d_lo = *(const i32x4*)&dst[e0];
    i32x4 d_hi = *(const i32x4*)&dst[e0 + 4];
    __builtin_amdgcn_sched_barrier(0);

    // Phase 2: all 16 gathers back-to-back (h half is L2-resident)
    f32x4 a[U], bb[U];
#pragma unroll
    for (int u = 0; u < U; u++) {
        int es = (u < 4) ? s_lo[u & 3] : s_hi[u & 3];
        int ed = (u < 4) ? d_lo[u & 3] : d_hi[u & 3];
        a[u]  = h4[es * 32 + c];
        bb[u] = h4[ed * 32 + c];
    }
    __builtin_amdgcn_sched_barrier(0);

    // Phase 3: multiply + nontemporal streaming stores (256 B segments)
#pragma unroll
    for (int u = 0; u < U; u++) {
        __builtin_nontemporal_store(a[u] * bb[u], &out4[(e0 + u) * 32 + c]);
    }
}

// Generic fallback (any shape).
__global__ __launch_bounds__(BLOCK) void u_mul_v_generic(
    const f32x4* __restrict__ h4,
    const int* __restrict__ src,
    const int* __restrict__ dst,
    f32x4* __restrict__ out4,
    int n_f4)
{
    int stride = gridDim.x * BLOCK;
    for (int i = blockIdx.x * BLOCK + threadIdx.x; i < n_f4; i += stride) {
        int e = i >> 5, cc = i & 31;
        f32x4 a = h4[src[e] * 32 + cc];
        f32x4 bv = h4[dst[e] * 32 + cc];
        out4[i] = a * bv;
    }
}

extern "C" void kernel_launch(void* const* d_in, const int* in_sizes, int n_in,
                              void* d_out, int out_size, void* d_ws, size_t ws_size,
                              hipStream_t stream) {
    const f32x4* h4 = (const f32x4*)d_in[0];
    const int* src  = (const int*)d_in[1];
    const int* dst  = (const int*)d_in[2];
    f32x4* out4     = (f32x4*)d_out;

    int n_edges = in_sizes[1];            // 640000
    int n_f4 = n_edges * 32;

    if (n_edges % EDGES_PER_BLOCK == 0) {
        int g_half = n_edges / EDGES_PER_BLOCK;   // 5000
        int grid = 2 * g_half;                    // 10000 blocks
        u_mul_v_split<<<grid, BLOCK, 0, stream>>>(h4, src, dst, out4);
    } else {
        u_mul_v_generic<<<2048, BLOCK, 0, stream>>>(h4, src, dst, out4, n_f4);
    }
}